// Round 3
// baseline (464.923 us; speedup 1.0000x reference)
//
#include <hip/hip_runtime.h>

// RAFilter: I_RA[t] = a * I_RA[t-1] + c * |I[t] - I[t-1]|, I[-1] = 0, I_RA[-1] = 0
// a = 1 - DT/TAU_RA, c = K3/TAU_RA   (the DT in drive cancels with the /DT in dI)
// Shapes: (B=8, T=4096, N=2048) float32. Chain = (b, n) pair, serial over t.
//
// Strategy: one thread per chain (16384 threads = 256 blocks x 64), coalesced
// across n (64 lanes read 256B contiguous per time step). Latency hidden via
// double-buffered unroll-32 prefetch (~8-16KB in flight per CU); memory-bound
// target ~81us (512MB @ 6.3TB/s).

constexpr int Bb = 8;
constexpr int Tn = 4096;
constexpr int Nn = 2048;
constexpr int UNROLL = 32;

__global__ __launch_bounds__(64) void ra_filter_kernel(
    const float* __restrict__ in, float* __restrict__ out) {
    const int gid = blockIdx.x * 64 + threadIdx.x;   // chain id in [0, B*N)
    const int b = gid >> 11;                          // gid / 2048
    const int n = gid & (Nn - 1);                     // gid % 2048

    const size_t base = (size_t)b * Tn * Nn + n;
    const float* p = in + base;
    float* q = out + base;

    const float a = (float)(1.0 - 0.1 / 30.0);        // 0.99666667
    const float c = (float)(2.0 / 30.0);              // 0.06666667

    float xa[UNROLL], xb[UNROLL];
    float prev = 0.0f, state = 0.0f;

    // prime: load first chunk (t = 0..U-1)
#pragma unroll
    for (int u = 0; u < UNROLL; ++u)
        xa[u] = __builtin_nontemporal_load(p + (size_t)u * Nn);

    // two chunks per outer iteration; 4096 / 64 = 64 iterations worth of chunks
    for (int t0 = 0; t0 < Tn; t0 += 2 * UNROLL) {
        // prefetch chunk t0+U into xb
#pragma unroll
        for (int u = 0; u < UNROLL; ++u)
            xb[u] = __builtin_nontemporal_load(p + (size_t)(t0 + UNROLL + u) * Nn);

        // process + store chunk t0 (in xa)
#pragma unroll
        for (int u = 0; u < UNROLL; ++u) {
            float x = xa[u];
            float d = x - prev;
            prev = x;
            state = fmaf(a, state, c * fabsf(d));
            xa[u] = state;
        }
#pragma unroll
        for (int u = 0; u < UNROLL; ++u)
            __builtin_nontemporal_store(xa[u], q + (size_t)(t0 + u) * Nn);

        // prefetch chunk t0+2U into xa (skip past end)
        if (t0 + 2 * UNROLL < Tn) {
#pragma unroll
            for (int u = 0; u < UNROLL; ++u)
                xa[u] = __builtin_nontemporal_load(p + (size_t)(t0 + 2 * UNROLL + u) * Nn);
        }

        // process + store chunk t0+U (in xb)
#pragma unroll
        for (int u = 0; u < UNROLL; ++u) {
            float x = xb[u];
            float d = x - prev;
            prev = x;
            state = fmaf(a, state, c * fabsf(d));
            xb[u] = state;
        }
#pragma unroll
        for (int u = 0; u < UNROLL; ++u)
            __builtin_nontemporal_store(xb[u], q + (size_t)(t0 + UNROLL + u) * Nn);
    }
}

extern "C" void kernel_launch(void* const* d_in, const int* in_sizes, int n_in,
                              void* d_out, int out_size, void* d_ws, size_t ws_size,
                              hipStream_t stream) {
    const float* in = (const float*)d_in[0];
    float* out = (float*)d_out;

    const int chains = Bb * Nn;                 // 16384
    dim3 grid(chains / 64), block(64);          // 256 blocks x 64 threads
    hipLaunchKernelGGL(ra_filter_kernel, grid, block, 0, stream, in, out);
}